// Round 11
// baseline (653.127 us; speedup 1.0000x reference)
//
#include <hip/hip_runtime.h>

// RGCN: N=50000, E=1.6M, R=8, 128 -> 64 -> 64.
// R11: aggregate-then-transform. Per layer, ONE fused kernel:
//   edge phase: wave walks its dst's (rel-sorted) CSR run list, accumulates
//     raw neighbor sums in registers, flushes each (d,r) run to LDS S tile
//     (scaled by inv) on rel change -- no atomics, uniform branches.
//     Gather set = xb (12.8MB) / hb (6.4MB): L2/L3-hot (vs 51.2MB xw before).
//   GEMM phase: out[tile] = S[tile][9*K_in] @ Wcat^T via 16x16x32 bf16 MFMA,
//     A from LDS, B from L2-hot Wt, root as group 9, bias/relu fused.
// Eliminates xw (51.2MB writes + 105MB-FETCH gathers) and 2 kernels.
// CSR build (block-reserved staged append, fixed-cap buckets) as R10.

constexpr int NN  = 50000;
constexpr int NE  = 1600000;
constexpr int NR  = 8;
constexpr int FIN = 128;
constexpr int FH  = 64;

constexpr int BSH = 7;                       // 128 dst nodes per bucket
constexpr int BN  = 1 << BSH;
constexpr int NB  = (NN + BN - 1) >> BSH;    // 391
constexpr int CAP = 6144;                    // bucket capacity (load ~4092±64)
constexpr int CH  = 8192;                    // edges per append block

typedef __attribute__((ext_vector_type(8))) short bf16x8;
typedef __attribute__((ext_vector_type(4))) float f32x4;

__device__ __forceinline__ unsigned short f2bf(float f) {
  unsigned u = __float_as_uint(f);
  u = (u + 0x7fff + ((u >> 16) & 1)) >> 16;   // RNE
  return (unsigned short)u;
}
__device__ __forceinline__ float bf2f(unsigned short b) {
  return __uint_as_float(((unsigned)b) << 16);
}
__device__ __forceinline__ bool edge_ok(unsigned s, unsigned d, unsigned r) {
  return s < NN && d < NN && r < NR;
}

// ---------------- CSR build (unchanged from R10) ----------------
__global__ void bcur_init(int* __restrict__ bcur) {
  const int i = blockIdx.x * blockDim.x + threadIdx.x;
  if (i < NB) bcur[i] = i * CAP;
}

__global__ void __launch_bounds__(256) bucket_append(
    const int* __restrict__ src, const int* __restrict__ dst,
    const int* __restrict__ et, int* __restrict__ bcur,
    uint2* __restrict__ brecs) {
  __shared__ uint2 stage[CH];                  // 64 KB
  __shared__ int h[NB], gbase[NB], sbase[NB], scur[NB];
  __shared__ int wtot[4];
  const int t  = threadIdx.x;
  const int c0 = blockIdx.x * CH;
  const int m  = min(CH, NE - c0);

  for (int i = t; i < NB; i += 256) h[i] = 0;
  __syncthreads();

  for (int i = t; i < m; i += 256) {
    const unsigned s = (unsigned)src[c0 + i];
    const unsigned d = (unsigned)dst[c0 + i];
    const unsigned r = (unsigned)et[c0 + i];
    if (edge_ok(s, d, r)) atomicAdd(&h[d >> BSH], 1);
  }
  __syncthreads();

  const int v0 = (2 * t < NB) ? h[2 * t] : 0;
  const int v1 = (2 * t + 1 < NB) ? h[2 * t + 1] : 0;
  if (2 * t < NB     && v0) gbase[2 * t]     = atomicAdd(&bcur[2 * t], v0);
  if (2 * t + 1 < NB && v1) gbase[2 * t + 1] = atomicAdd(&bcur[2 * t + 1], v1);
  const int s = v0 + v1;
  int incl = s;
#pragma unroll
  for (int o = 1; o < 64; o <<= 1) {
    int u = __shfl_up(incl, o, 64);
    if ((t & 63) >= o) incl += u;
  }
  if ((t & 63) == 63) wtot[t >> 6] = incl;
  __syncthreads();
  int wo = 0;
  for (int w = 0; w < (t >> 6); ++w) wo += wtot[w];
  const int e = wo + incl - s;
  if (2 * t < NB)     { sbase[2 * t] = e;          scur[2 * t] = e; }
  if (2 * t + 1 < NB) { sbase[2 * t + 1] = e + v0; scur[2 * t + 1] = e + v0; }
  __syncthreads();

  for (int i = t; i < m; i += 256) {
    const unsigned sv = (unsigned)src[c0 + i];
    const unsigned d  = (unsigned)dst[c0 + i];
    const unsigned r  = (unsigned)et[c0 + i];
    if (edge_ok(sv, d, r)) {
      const int p = atomicAdd(&scur[d >> BSH], 1);
      if (p < CH) stage[p] = make_uint2((sv << 9) | (r << 6), d);
    }
  }
  __syncthreads();

  const int M = min(sbase[NB - 1] + h[NB - 1], CH);
  for (int j = t; j < M; j += 256) {
    const uint2 rec = stage[j];
    const int b = (int)(rec.y >> BSH);
    const int idx = min(gbase[b] + (j - sbase[b]), NB * CAP - 1);
    brecs[idx] = rec;
  }
}

__global__ void __launch_bounds__(256) bucket_finalize(
    const int* __restrict__ bcur, const uint2* __restrict__ brecs,
    float* __restrict__ inv, int* __restrict__ row_start,
    int* __restrict__ deg, unsigned* __restrict__ recs) {
  const int b    = blockIdx.x;
  const int base = b * CAP;
  const int m    = min(bcur[b] - base, CAP);
  const int d0   = b << BSH;
  __shared__ int cnt[BN * NR];
  __shared__ int curs[BN * NR];
  __shared__ int wtot[4];
  const int t = threadIdx.x;

  for (int i = t; i < BN * NR; i += 256) cnt[i] = 0;
  __syncthreads();
  for (int i = t; i < m; i += 256) {
    const uint2 rec = brecs[base + i];
    const int dl = (int)(rec.y & (BN - 1));
    const int r  = (rec.x >> 6) & 7;
    atomicAdd(&cnt[dl * NR + r], 1);
  }
  __syncthreads();

  const int c0 = cnt[t * 4], c1 = cnt[t * 4 + 1], c2 = cnt[t * 4 + 2], c3 = cnt[t * 4 + 3];
  const int s = c0 + c1 + c2 + c3;
  int incl = s;
#pragma unroll
  for (int o = 1; o < 64; o <<= 1) {
    int u = __shfl_up(incl, o, 64);
    if ((t & 63) >= o) incl += u;
  }
  if ((t & 63) == 63) wtot[t >> 6] = incl;
  __syncthreads();
  int wo = 0;
  for (int w = 0; w < (t >> 6); ++w) wo += wtot[w];
  const int e = wo + incl - s;
  curs[t * 4]     = e;
  curs[t * 4 + 1] = e + c0;
  curs[t * 4 + 2] = e + c0 + c1;
  curs[t * 4 + 3] = e + c0 + c1 + c2;
  __syncthreads();

  if (t < BN) {
    const int d = d0 + t;
    if (d < NN) {
      const int start = curs[t * NR];
      const int end   = (t == BN - 1) ? m : curs[(t + 1) * NR];
      row_start[d] = base + start;
      deg[d]       = end - start;
#pragma unroll
      for (int r = 0; r < NR; ++r)
        inv[d * NR + r] = 1.0f / fmaxf((float)cnt[t * NR + r], 1.0f);
    }
  }
  __syncthreads();

  for (int i = t; i < m; i += 256) {
    const uint2 rec = brecs[base + i];
    const int dl = (int)(rec.y & (BN - 1));
    const int r  = (rec.x >> 6) & 7;
    const int p  = atomicAdd(&curs[dl * NR + r], 1);
    recs[base + min(p, CAP - 1)] = rec.x;
  }
}

// ---------------- prep: x -> bf16, weights -> bf16 transposed ----------------
__global__ void prep(const float* __restrict__ x,
                     const float* __restrict__ W1r, const float* __restrict__ W1o,
                     const float* __restrict__ W2r, const float* __restrict__ W2o,
                     unsigned short* __restrict__ xb,
                     unsigned short* __restrict__ Wt1,
                     unsigned short* __restrict__ Wt2) {
  const int i   = blockIdx.x * blockDim.x + threadIdx.x;
  const int NX  = NN * FIN / 4;            // 1,600,000 float4 groups
  const int NW1 = (NR + 1) * 64 * FIN;     // 73,728
  const int NW2 = (NR + 1) * 64 * FH;      // 36,864
  if (i < NX) {
    const float4 v = ((const float4*)x)[i];
    ushort4 o;
    o.x = f2bf(v.x); o.y = f2bf(v.y); o.z = f2bf(v.z); o.w = f2bf(v.w);
    ((ushort4*)xb)[i] = o;
  } else if (i < NX + NW1) {
    const int j = i - NX;
    const int g = j / (64 * FIN), rem = j % (64 * FIN);
    const int n = rem / FIN, k = rem % FIN;
    const float* W = (g < NR) ? (W1r + (size_t)g * FIN * 64) : W1o;
    Wt1[j] = f2bf(W[k * 64 + n]);
  } else if (i < NX + NW1 + NW2) {
    const int j = i - NX - NW1;
    const int g = j / (64 * FH), rem = j % (64 * FH);
    const int n = rem / FH, k = rem % FH;
    const float* W = (g < NR) ? (W2r + (size_t)g * FH * 64) : W2o;
    Wt2[j] = f2bf(W[k * 64 + n]);
  }
}

// ---------------- fused layer: aggregate-then-transform ----------------
// Block owns MTILE dst nodes. Edge phase: wave walks each owned dst's
// rel-sorted run list, register-accumulates, flushes runs (scaled) to LDS
// S[MTILE][(NR+1)*K_IN] bf16 (root = group NR). GEMM phase: 16x16x32 MFMA,
// A from LDS S, B from L2-hot Wt; bias (+relu->bf16 | fp32) epilogue.
template <int K_IN, int MTILE, bool RELU_BF16>
__global__ void __launch_bounds__(256) fused_layer(
    const int* __restrict__ row_start, const int* __restrict__ deg,
    const unsigned* __restrict__ offs, const float* __restrict__ inv,
    const unsigned short* __restrict__ fin,   // [NN][K_IN] bf16
    const unsigned short* __restrict__ Wt,    // [(NR+1)][64][K_IN] bf16
    const float* __restrict__ bias,
    unsigned short* __restrict__ out_b16, float* __restrict__ out_f32) {
  constexpr int SROW = (NR + 1) * K_IN + 8;   // +16B pad
  __shared__ unsigned short S[MTILE * SROW];
  const int n0  = blockIdx.x * MTILE;
  const int tid = threadIdx.x;
  const int wave = tid >> 6, lane = tid & 63;

  // zero S
  for (int i = tid * 8; i < MTILE * SROW; i += 2048)
    *(bf16x8*)(S + i) = (bf16x8){};
  __syncthreads();

  // root group: S[dl][NR*K_IN + k] = fin[d][k]
  for (int i = tid; i < MTILE * (K_IN / 8); i += 256) {
    const int dl = i / (K_IN / 8), kp = (i % (K_IN / 8)) * 8;
    const int d = n0 + dl;
    bf16x8 v = {};
    if (d < NN) v = *(const bf16x8*)(fin + (size_t)d * K_IN + kp);
    *(bf16x8*)(S + dl * SROW + NR * K_IN + kp) = v;
  }

  // edge phase: wave w handles dl = w, w+4, ...
  for (int dl = wave; dl < MTILE; dl += 4) {
    const int d = n0 + dl;
    if (d >= NN) break;
    const int base = row_start[d];
    const int n    = deg[d];
    unsigned short* Srow = S + dl * SROW;
    float a0 = 0.f, a1 = 0.f;
    int cur = -1;
    for (int c = 0; c < n; c += 64) {
      const int m = min(64, n - c);
      unsigned rec = 0;
      if (lane < m) rec = offs[base + c + lane];
      for (int j = 0; j < m; ++j) {
        const unsigned u  = __shfl(rec, j, 64);
        const int      r  = (int)((u >> 6) & 7);
        const unsigned sv = u >> 9;                 // src node (< NN by append guard)
        if (r != cur) {                             // wave-uniform branch
          if (cur >= 0) {
            const float sc = inv[(d << 3) + cur];
            if constexpr (K_IN == 128) {
              const unsigned pk = ((unsigned)f2bf(a1 * sc) << 16) | f2bf(a0 * sc);
              *(unsigned*)(Srow + cur * K_IN + lane * 2) = pk;
            } else {
              Srow[cur * K_IN + lane] = f2bf(a0 * sc);
            }
          }
          cur = r; a0 = 0.f; a1 = 0.f;
        }
        if constexpr (K_IN == 128) {
          const unsigned v = *(const unsigned*)(fin + (size_t)sv * K_IN + lane * 2);
          a0 += bf2f((unsigned short)(v & 0xffffu));
          a1 += bf2f((unsigned short)(v >> 16));
        } else {
          a0 += bf2f(fin[(size_t)sv * K_IN + lane]);
        }
      }
    }
    if (cur >= 0) {
      const float sc = inv[(d << 3) + cur];
      if constexpr (K_IN == 128) {
        const unsigned pk = ((unsigned)f2bf(a1 * sc) << 16) | f2bf(a0 * sc);
        *(unsigned*)(Srow + cur * K_IN + lane * 2) = pk;
      } else {
        Srow[cur * K_IN + lane] = f2bf(a0 * sc);
      }
    }
  }
  __syncthreads();

  // GEMM phase: out[m][col] = sum_g sum_k S[m][g*K_IN+k] * Wt[g][col][k]
  const int i16 = lane & 15, quad = lane >> 4;
  constexpr int MT = MTILE / 16;
  f32x4 acc[MT] = {};
#pragma unroll
  for (int g = 0; g <= NR; ++g) {
#pragma unroll
    for (int kc = 0; kc < K_IN / 32; ++kc) {
      const int ko = g * K_IN + kc * 32 + quad * 8;
      const bf16x8 b = *(const bf16x8*)(
          Wt + (size_t)(g * 64 + wave * 16 + i16) * K_IN + kc * 32 + quad * 8);
#pragma unroll
      for (int mt = 0; mt < MT; ++mt) {
        const bf16x8 a = *(const bf16x8*)(S + (mt * 16 + i16) * SROW + ko);
        acc[mt] = __builtin_amdgcn_mfma_f32_16x16x32_bf16(a, b, acc[mt], 0, 0, 0);
      }
    }
  }

  // epilogue: C/D row = quad*4+reg, col = wave*16 + i16
  const int col = wave * 16 + i16;
  const float bv = bias[col];
#pragma unroll
  for (int mt = 0; mt < MT; ++mt) {
#pragma unroll
    for (int reg = 0; reg < 4; ++reg) {
      const int d = n0 + mt * 16 + quad * 4 + reg;
      if (d >= NN) continue;
      const float h = acc[mt][reg] + bv;
      if constexpr (RELU_BF16)
        out_b16[(size_t)d * 64 + col] = f2bf(fmaxf(h, 0.f));
      else
        out_f32[(size_t)d * 64 + col] = h;
    }
  }
}

extern "C" void kernel_launch(void* const* d_in, const int* in_sizes, int n_in,
                              void* d_out, int out_size, void* d_ws, size_t ws_size,
                              hipStream_t stream) {
  const float* x   = (const float*)d_in[0];
  const int*   ei  = (const int*)d_in[1];
  const int*   et  = (const int*)d_in[2];
  const float* W1r = (const float*)d_in[3];
  const float* W1o = (const float*)d_in[4];
  const float* b1  = (const float*)d_in[5];
  const float* W2r = (const float*)d_in[6];
  const float* W2o = (const float*)d_in[7];
  const float* b2  = (const float*)d_in[8];
  float* out = (float*)d_out;

  const int* src = ei;
  const int* dst = ei + NE;

  char* ws = (char*)d_ws;
  size_t off = 0;
  auto alloc = [&](size_t bytes) {
    void* p = ws + off; off += (bytes + 255) & ~(size_t)255; return p;
  };
  int*   bcur      = (int*)alloc((size_t)NB * 4);
  float* inv       = (float*)alloc((size_t)NN * NR * 4);
  int*   row_start = (int*)alloc((size_t)NN * 4);
  int*   deg       = (int*)alloc((size_t)NN * 4);
  uint2* brecs     = (uint2*)alloc((size_t)NB * CAP * 8);                 // 19.2 MB
  unsigned* offs   = (unsigned*)alloc((size_t)NB * CAP * 4);              //  9.6 MB
  unsigned short* xb  = (unsigned short*)alloc((size_t)NN * FIN * 2);     // 12.8 MB
  unsigned short* hb  = (unsigned short*)alloc((size_t)NN * FH * 2);      //  6.4 MB
  unsigned short* Wt1 = (unsigned short*)alloc((size_t)(NR + 1) * 64 * FIN * 2);
  unsigned short* Wt2 = (unsigned short*)alloc((size_t)(NR + 1) * 64 * FH * 2);

  bcur_init<<<(NB + 255) / 256, 256, 0, stream>>>(bcur);
  bucket_append<<<(NE + CH - 1) / CH, 256, 0, stream>>>(src, dst, et, bcur, brecs);
  bucket_finalize<<<NB, 256, 0, stream>>>(bcur, brecs, inv, row_start, deg, offs);

  const int nprep = NN * FIN / 4 + (NR + 1) * 64 * (FIN + FH);
  prep<<<(nprep + 255) / 256, 256, 0, stream>>>(x, W1r, W1o, W2r, W2o, xb, Wt1, Wt2);

  // Layer 1: 16 dst/block, K=9*128=1152, out = relu(h) bf16
  fused_layer<FIN, 16, true><<<(NN + 15) / 16, 256, 0, stream>>>(
      row_start, deg, offs, inv, xb, Wt1, b1, hb, nullptr);
  // Layer 2: 32 dst/block, K=9*64=576, out = fp32
  fused_layer<FH, 32, false><<<(NN + 31) / 32, 256, 0, stream>>>(
      row_start, deg, offs, inv, hb, Wt2, b2, nullptr, out);
}

// Round 12
// 252.298 us; speedup vs baseline: 2.5887x; 2.5887x over previous
//
#include <hip/hip_runtime.h>

// RGCN: N=50000, E=1.6M, R=8, 128 -> 64 -> 64.
// R12 = R10 (known-good 254us: 8-edge vectorized agg, dbuf-B MFMA gemm,
// block-reserved bucketed CSR) + CSR-build cuts:
//   - append CH 8192->4096: 391 blocks (~4/CU) instead of 196 (<1/CU)
//   - brecs packed to 4B (sv<<10|dl<<3|r): halves append write + finalize read
//   - bcur_init merged into prep (one fewer dispatch)
// R11's aggregate-then-transform reverted (latency-serialized edge walk:
// 1 outstanding gather/wave vs 8 here -- 284us/layer, lesson logged).

constexpr int NN  = 50000;
constexpr int NE  = 1600000;
constexpr int NR  = 8;
constexpr int FIN = 128;
constexpr int FH  = 64;

constexpr int BSH = 7;                       // 128 dst nodes per bucket
constexpr int BN  = 1 << BSH;
constexpr int NB  = (NN + BN - 1) >> BSH;    // 391
constexpr int CAP = 6144;                    // bucket capacity (load ~4092±64)
constexpr int CH  = 4096;                    // edges per append block
constexpr unsigned XWMAX = (unsigned)(NN - 1) * (NR * 64) + (NR - 1) * 64;

typedef __attribute__((ext_vector_type(8))) short bf16x8;
typedef __attribute__((ext_vector_type(4))) float f32x4;

__device__ __forceinline__ unsigned short f2bf(float f) {
  unsigned u = __float_as_uint(f);
  u = (u + 0x7fff + ((u >> 16) & 1)) >> 16;   // RNE
  return (unsigned short)u;
}
__device__ __forceinline__ float bf2f(unsigned short b) {
  return __uint_as_float(((unsigned)b) << 16);
}
__device__ __forceinline__ bool edge_ok(unsigned s, unsigned d, unsigned r) {
  return s < NN && d < NN && r < NR;
}

// ---------------- CSR build ----------------
// Block-staged append: per-block LDS hist, one global atomic per
// (block,bucket) span reservation, LDS-staged bucket-grouped records,
// coalesced 4B-packed write-out into fixed-capacity bucket windows.
__global__ void __launch_bounds__(256) bucket_append(
    const int* __restrict__ src, const int* __restrict__ dst,
    const int* __restrict__ et, int* __restrict__ bcur,
    unsigned* __restrict__ brecs) {
  __shared__ uint2 stage[CH];                  // 32 KB
  __shared__ int h[NB], gbase[NB], sbase[NB], scur[NB];
  __shared__ int wtot[4];
  const int t  = threadIdx.x;
  const int c0 = blockIdx.x * CH;
  const int m  = min(CH, NE - c0);

  for (int i = t; i < NB; i += 256) h[i] = 0;
  __syncthreads();

  // pass A: per-block bucket histogram
  for (int i = t; i < m; i += 256) {
    const unsigned s = (unsigned)src[c0 + i];
    const unsigned d = (unsigned)dst[c0 + i];
    const unsigned r = (unsigned)et[c0 + i];
    if (edge_ok(s, d, r)) atomicAdd(&h[d >> BSH], 1);
  }
  __syncthreads();

  // reserve spans + block-local exclusive scan (2 buckets per thread)
  const int v0 = (2 * t < NB) ? h[2 * t] : 0;
  const int v1 = (2 * t + 1 < NB) ? h[2 * t + 1] : 0;
  if (2 * t < NB     && v0) gbase[2 * t]     = atomicAdd(&bcur[2 * t], v0);
  if (2 * t + 1 < NB && v1) gbase[2 * t + 1] = atomicAdd(&bcur[2 * t + 1], v1);
  const int s = v0 + v1;
  int incl = s;
#pragma unroll
  for (int o = 1; o < 64; o <<= 1) {
    int u = __shfl_up(incl, o, 64);
    if ((t & 63) >= o) incl += u;
  }
  if ((t & 63) == 63) wtot[t >> 6] = incl;
  __syncthreads();
  int wo = 0;
  for (int w = 0; w < (t >> 6); ++w) wo += wtot[w];
  const int e = wo + incl - s;
  if (2 * t < NB)     { sbase[2 * t] = e;          scur[2 * t] = e; }
  if (2 * t + 1 < NB) { sbase[2 * t + 1] = e + v0; scur[2 * t + 1] = e + v0; }
  __syncthreads();

  // pass B: stage records grouped by bucket
  for (int i = t; i < m; i += 256) {
    const unsigned sv = (unsigned)src[c0 + i];
    const unsigned d  = (unsigned)dst[c0 + i];
    const unsigned r  = (unsigned)et[c0 + i];
    if (edge_ok(sv, d, r)) {
      const int p = atomicAdd(&scur[d >> BSH], 1);
      if (p < CH) stage[p] = make_uint2((sv << 10) | (((unsigned)d & (BN - 1)) << 3) | r, d);
    }
  }
  __syncthreads();

  // write-out: consecutive j -> consecutive global addresses (4B packed)
  const int M = min(sbase[NB - 1] + h[NB - 1], CH);
  for (int j = t; j < M; j += 256) {
    const uint2 rec = stage[j];
    const int b = (int)(rec.y >> BSH);
    const int idx = min(gbase[b] + (j - sbase[b]), NB * CAP - 1);
    brecs[idx] = rec.x;
  }
}

// One block per bucket: count per (dlocal, r) in LDS, scan, emit
// inv/deg/row_start, place final 4B records into the bucket window.
__global__ void __launch_bounds__(256) bucket_finalize(
    const int* __restrict__ bcur, const unsigned* __restrict__ brecs,
    float* __restrict__ inv, int* __restrict__ row_start,
    int* __restrict__ deg, unsigned* __restrict__ recs) {
  const int b    = blockIdx.x;
  const int base = b * CAP;
  const int m    = min(bcur[b] - base, CAP);
  const int d0   = b << BSH;
  __shared__ int cnt[BN * NR];
  __shared__ int curs[BN * NR];
  __shared__ int wtot[4];
  const int t = threadIdx.x;

  for (int i = t; i < BN * NR; i += 256) cnt[i] = 0;
  __syncthreads();
  for (int i = t; i < m; i += 256) {
    const unsigned rec = brecs[base + i];
    const int dl = (int)((rec >> 3) & (BN - 1));
    const int r  = (int)(rec & 7);
    atomicAdd(&cnt[dl * NR + r], 1);
  }
  __syncthreads();

  const int c0 = cnt[t * 4], c1 = cnt[t * 4 + 1], c2 = cnt[t * 4 + 2], c3 = cnt[t * 4 + 3];
  const int s = c0 + c1 + c2 + c3;
  int incl = s;
#pragma unroll
  for (int o = 1; o < 64; o <<= 1) {
    int u = __shfl_up(incl, o, 64);
    if ((t & 63) >= o) incl += u;
  }
  if ((t & 63) == 63) wtot[t >> 6] = incl;
  __syncthreads();
  int wo = 0;
  for (int w = 0; w < (t >> 6); ++w) wo += wtot[w];
  const int e = wo + incl - s;
  curs[t * 4]     = e;
  curs[t * 4 + 1] = e + c0;
  curs[t * 4 + 2] = e + c0 + c1;
  curs[t * 4 + 3] = e + c0 + c1 + c2;
  __syncthreads();

  if (t < BN) {
    const int d = d0 + t;
    if (d < NN) {
      const int start = curs[t * NR];
      const int end   = (t == BN - 1) ? m : curs[(t + 1) * NR];
      row_start[d] = base + start;
      deg[d]       = end - start;
#pragma unroll
      for (int r = 0; r < NR; ++r)
        inv[d * NR + r] = 1.0f / fmaxf((float)cnt[t * NR + r], 1.0f);
    }
  }
  __syncthreads();

  for (int i = t; i < m; i += 256) {
    const unsigned rec = brecs[base + i];
    const int dl = (int)((rec >> 3) & (BN - 1));
    const int r  = (int)(rec & 7);
    const unsigned sv = rec >> 10;
    const int p  = atomicAdd(&curs[dl * NR + r], 1);
    recs[base + min(p, CAP - 1)] = (sv << 9) | ((unsigned)r << 6);
  }
}

// ---------------- prep: bcur init + weights -> bf16 transposed ----------------
// W[g][k][n] fp32 -> Wt[g][n][k] bf16 (g<NR rel, g==NR root).
__global__ void prep(const float* __restrict__ W1r, const float* __restrict__ W1o,
                     const float* __restrict__ W2r, const float* __restrict__ W2o,
                     unsigned short* __restrict__ Wt1,
                     unsigned short* __restrict__ Wt2,
                     int* __restrict__ bcur) {
  const int i  = blockIdx.x * blockDim.x + threadIdx.x;
  if (i < NB) bcur[i] = i * CAP;
  const int n1 = (NR + 1) * 64 * FIN;
  const int n2 = (NR + 1) * 64 * FH;
  if (i < n1) {
    const int g = i / (64 * FIN), rem = i % (64 * FIN);
    const int n = rem / FIN, k = rem % FIN;
    const float* W = (g < NR) ? (W1r + (size_t)g * FIN * 64) : W1o;
    Wt1[i] = f2bf(W[k * 64 + n]);
  } else if (i < n1 + n2) {
    const int j = i - n1;
    const int g = j / (64 * FH), rem = j % (64 * FH);
    const int n = rem / FH, k = rem % FH;
    const float* W = (g < NR) ? (W2r + (size_t)g * FH * 64) : W2o;
    Wt2[j] = f2bf(W[k * 64 + n]);
  }
}

// ---------------- MFMA GEMM (unchanged from R10) ----------------
template <int K, bool A_FP32>
__global__ void __launch_bounds__(256) gemm_mfma(
    const void* __restrict__ Av, const unsigned short* __restrict__ Wt,
    const float* __restrict__ bias,
    unsigned short* __restrict__ xw, float* __restrict__ root_out) {
  constexpr int KP  = K + 8;
  constexpr int NCH = 64 * (K / 8) / 256;   // B chunks per thread (4 / 2)
  __shared__ unsigned short As[64 * KP];
  __shared__ unsigned short Bs[2][64 * KP];
  const int n0  = blockIdx.x * 64;
  const int tid = threadIdx.x;

  if constexpr (A_FP32) {
    const float* A = (const float*)Av;
    for (int c = tid; c < 64 * (K / 8); c += 256) {
      const int row = c / (K / 8), kp = (c % (K / 8)) * 8;
      bf16x8 v = {};
      if (n0 + row < NN) {
        const float* p = A + (size_t)(n0 + row) * K + kp;
        const float4 f0 = *(const float4*)p;
        const float4 f1 = *(const float4*)(p + 4);
        v[0] = f2bf(f0.x); v[1] = f2bf(f0.y); v[2] = f2bf(f0.z); v[3] = f2bf(f0.w);
        v[4] = f2bf(f1.x); v[5] = f2bf(f1.y); v[6] = f2bf(f1.z); v[7] = f2bf(f1.w);
      }
      *(bf16x8*)(As + row * KP + kp) = v;
    }
  } else {
    const unsigned short* A = (const unsigned short*)Av;
    for (int c = tid; c < 64 * (K / 8); c += 256) {
      const int row = c / (K / 8), kp = (c % (K / 8)) * 8;
      bf16x8 v = {};
      if (n0 + row < NN) v = *(const bf16x8*)(A + (size_t)(n0 + row) * K + kp);
      *(bf16x8*)(As + row * KP + kp) = v;
    }
  }

  // stage B group 0 into Bs[0]
  for (int c = 0; c < NCH; ++c) {
    const int idx = tid + c * 256;
    const int row = idx / (K / 8), kp = (idx % (K / 8)) * 8;
    *(bf16x8*)(Bs[0] + row * KP + kp) = *(const bf16x8*)(Wt + idx * 8);
  }
  __syncthreads();

  const int wave = tid >> 6, lane = tid & 63;
  const int i16 = lane & 15, quad = lane >> 4;
  const int r0 = wave * 16 + i16;

  for (int g = 0; g <= NR; ++g) {
    const int buf = g & 1;
    bf16x8 breg[NCH];
    if (g < NR) {
      const unsigned short* Wn = Wt + (size_t)(g + 1) * 64 * K;
#pragma unroll
      for (int c = 0; c < NCH; ++c) breg[c] = *(const bf16x8*)(Wn + (tid + c * 256) * 8);
    }

    f32x4 acc[4] = {};
#pragma unroll
    for (int kc = 0; kc < K / 32; ++kc) {
      const int k0 = kc * 32 + quad * 8;
      const bf16x8 a0 = *(const bf16x8*)(As + r0 * KP + k0);
      const bf16x8 b0 = *(const bf16x8*)(Bs[buf] + (i16)      * KP + k0);
      const bf16x8 b1 = *(const bf16x8*)(Bs[buf] + (i16 + 16) * KP + k0);
      const bf16x8 b2 = *(const bf16x8*)(Bs[buf] + (i16 + 32) * KP + k0);
      const bf16x8 b3 = *(const bf16x8*)(Bs[buf] + (i16 + 48) * KP + k0);
      acc[0] = __builtin_amdgcn_mfma_f32_16x16x32_bf16(a0, b0, acc[0], 0, 0, 0);
      acc[1] = __builtin_amdgcn_mfma_f32_16x16x32_bf16(a0, b1, acc[1], 0, 0, 0);
      acc[2] = __builtin_amdgcn_mfma_f32_16x16x32_bf16(a0, b2, acc[2], 0, 0, 0);
      acc[3] = __builtin_amdgcn_mfma_f32_16x16x32_bf16(a0, b3, acc[3], 0, 0, 0);
    }

    if (g < NR) {
#pragma unroll
      for (int c = 0; c < NCH; ++c) {
        const int idx = tid + c * 256;
        const int row = idx / (K / 8), kp = (idx % (K / 8)) * 8;
        *(bf16x8*)(Bs[buf ^ 1] + row * KP + kp) = breg[c];
      }
    }

    if (g < NR) {
#pragma unroll
      for (int reg = 0; reg < 4; ++reg) {
        const int n = n0 + wave * 16 + quad * 4 + reg;
        if (n >= NN) continue;
        unsigned short* p = xw + (size_t)n * (NR * 64) + g * 64 + i16;
#pragma unroll
        for (int ct = 0; ct < 4; ++ct) p[ct * 16] = f2bf(acc[ct][reg]);
      }
    } else {
      float bv[4];
#pragma unroll
      for (int ct = 0; ct < 4; ++ct) bv[ct] = bias[ct * 16 + i16];
#pragma unroll
      for (int reg = 0; reg < 4; ++reg) {
        const int n = n0 + wave * 16 + quad * 4 + reg;
        if (n >= NN) continue;
        float* p = root_out + (size_t)n * 64 + i16;
#pragma unroll
        for (int ct = 0; ct < 4; ++ct) p[ct * 16] = acc[ct][reg] + bv[ct];
      }
    }
    __syncthreads();
  }
}

// ---------------- aggregation (unchanged from R10) ----------------
template <bool RELU_BF16>
__global__ void __launch_bounds__(256) agg_csr(
    const int* __restrict__ row_start, const int* __restrict__ deg,
    const unsigned* __restrict__ offs, const unsigned short* __restrict__ xw,
    const float* __restrict__ inv, const float* __restrict__ root,
    float* __restrict__ out_f32, unsigned short* __restrict__ out_b16) {
  const int gid  = blockIdx.x * blockDim.x + threadIdx.x;
  const int lane = gid & 63;
  const int d    = gid >> 6;
  if (d >= NN) return;
  const int e  = lane >> 3;
  const int l8 = lane & 7;
  const int base = row_start[d];
  const int n    = deg[d];
  const float invv = inv[(d << 3) + l8];
  float a[8] = {};

  for (int c = 0; c < n; c += 64) {
    const int m = min(64, n - c);
    unsigned off = 0;
    if (lane < m) off = offs[base + c + lane];
    for (int j = 0; j < m; j += 16) {
      const int i0 = j + e, i1 = j + 8 + e;
      unsigned u0 = __shfl(off, i0 & 63, 64);
      unsigned u1 = __shfl(off, i1 & 63, 64);
      float s0 = __shfl(invv, (int)((u0 >> 6) & 7), 64);
      float s1 = __shfl(invv, (int)((u1 >> 6) & 7), 64);
      u0 = min(u0, XWMAX); u1 = min(u1, XWMAX);   // safety clamp
      if (i0 >= m) s0 = 0.f;
      if (i1 >= m) s1 = 0.f;
      const bf16x8 v0 = *(const bf16x8*)(xw + u0 + l8 * 8);
      const bf16x8 v1 = *(const bf16x8*)(xw + u1 + l8 * 8);
#pragma unroll
      for (int q = 0; q < 8; ++q) a[q] += bf2f((unsigned short)v0[q]) * s0;
#pragma unroll
      for (int q = 0; q < 8; ++q) a[q] += bf2f((unsigned short)v1[q]) * s1;
    }
  }

#pragma unroll
  for (int q = 0; q < 8; ++q) {
    a[q] += __shfl_xor(a[q], 8, 64);
    a[q] += __shfl_xor(a[q], 16, 64);
    a[q] += __shfl_xor(a[q], 32, 64);
  }

  if (e == 0) {
    const float4 r0 = *(const float4*)(root + (size_t)d * 64 + l8 * 8);
    const float4 r1 = *(const float4*)(root + (size_t)d * 64 + l8 * 8 + 4);
    const float o[8] = {r0.x + a[0], r0.y + a[1], r0.z + a[2], r0.w + a[3],
                        r1.x + a[4], r1.y + a[5], r1.z + a[6], r1.w + a[7]};
    if (RELU_BF16) {
      bf16x8 ov;
#pragma unroll
      for (int q = 0; q < 8; ++q) ov[q] = (short)f2bf(fmaxf(o[q], 0.f));
      *(bf16x8*)(out_b16 + (size_t)d * 64 + l8 * 8) = ov;
    } else {
      *(float4*)(out_f32 + (size_t)d * 64 + l8 * 8)     = make_float4(o[0], o[1], o[2], o[3]);
      *(float4*)(out_f32 + (size_t)d * 64 + l8 * 8 + 4) = make_float4(o[4], o[5], o[6], o[7]);
    }
  }
}

extern "C" void kernel_launch(void* const* d_in, const int* in_sizes, int n_in,
                              void* d_out, int out_size, void* d_ws, size_t ws_size,
                              hipStream_t stream) {
  const float* x   = (const float*)d_in[0];
  const int*   ei  = (const int*)d_in[1];
  const int*   et  = (const int*)d_in[2];
  const float* W1r = (const float*)d_in[3];
  const float* W1o = (const float*)d_in[4];
  const float* b1  = (const float*)d_in[5];
  const float* W2r = (const float*)d_in[6];
  const float* W2o = (const float*)d_in[7];
  const float* b2  = (const float*)d_in[8];
  float* out = (float*)d_out;

  const int* src = ei;
  const int* dst = ei + NE;

  char* ws = (char*)d_ws;
  size_t off = 0;
  auto alloc = [&](size_t bytes) {
    void* p = ws + off; off += (bytes + 255) & ~(size_t)255; return p;
  };
  int*   bcur      = (int*)alloc((size_t)NB * 4);
  float* inv       = (float*)alloc((size_t)NN * NR * 4);
  int*   row_start = (int*)alloc((size_t)NN * 4);
  int*   deg       = (int*)alloc((size_t)NN * 4);
  unsigned* brecs  = (unsigned*)alloc((size_t)NB * CAP * 4);              //  9.6 MB
  unsigned* offs   = (unsigned*)alloc((size_t)NB * CAP * 4);              //  9.6 MB
  unsigned short* xw    = (unsigned short*)alloc((size_t)NN * NR * 64 * 2); // 51.2 MB
  unsigned short* hb    = (unsigned short*)alloc((size_t)NN * FH * 2);      //  6.4 MB
  float*          hroot = (float*)alloc((size_t)NN * 64 * 4);               // 12.8 MB
  unsigned short* Wt1   = (unsigned short*)alloc((size_t)(NR + 1) * 64 * FIN * 2);
  unsigned short* Wt2   = (unsigned short*)alloc((size_t)(NR + 1) * 64 * FH * 2);

  const int nprep = (NR + 1) * 64 * (FIN + FH);
  prep<<<(nprep + 255) / 256, 256, 0, stream>>>(W1r, W1o, W2r, W2o, Wt1, Wt2, bcur);
  bucket_append<<<(NE + CH - 1) / CH, 256, 0, stream>>>(src, dst, et, bcur, brecs);
  bucket_finalize<<<NB, 256, 0, stream>>>(bcur, brecs, inv, row_start, deg, offs);

  const int gemm_blocks = (NN + 63) / 64;
  const int agg_blocks  = (NN * 64 + 255) / 256;
  // Layer 1
  gemm_mfma<FIN, true><<<gemm_blocks, 256, 0, stream>>>(x, Wt1, b1, xw, hroot);
  agg_csr<true><<<agg_blocks, 256, 0, stream>>>(row_start, deg, offs, xw, inv, hroot, nullptr, hb);
  // Layer 2
  gemm_mfma<FH, false><<<gemm_blocks, 256, 0, stream>>>(hb, Wt2, b2, xw, out);
  agg_csr<false><<<agg_blocks, 256, 0, stream>>>(row_start, deg, offs, xw, inv, out, out, nullptr);
}